// Round 1
// baseline (577.938 us; speedup 1.0000x reference)
//
#include <hip/hip_runtime.h>
#include <math.h>

#define NLV 16
#define LOG2T 19
#define TSZ (1u << LOG2T)
#define TMASK (TSZ - 1u)
#define PRIME_Y 2654435761u

struct NGPParams {
    float scale[NLV];
    unsigned res[NLV];
    unsigned hashed_mask;
};

__global__ __launch_bounds__(256) void ngp_fused_kernel(
    const float2* __restrict__ uv,
    const float2* __restrict__ table,   // [16, 2^19] float2
    const float4* __restrict__ w0,      // 32x64 = 512 float4
    const float4* __restrict__ w1,      // 64x64 = 1024 float4
    const float*  __restrict__ w2,      // 64x3  = 192 float
    float* __restrict__ out,            // [N,3]
    NGPParams p, int n)
{
    __shared__ float4 sw0[512];
    __shared__ float4 sw1[1024];
    __shared__ float  sw2[192];

    const int t = threadIdx.x;
    #pragma unroll
    for (int i = 0; i < 2; i++) sw0[t + 256 * i] = w0[t + 256 * i];
    #pragma unroll
    for (int i = 0; i < 4; i++) sw1[t + 256 * i] = w1[t + 256 * i];
    if (t < 192) sw2[t] = w2[t];
    __syncthreads();

    const int gi = blockIdx.x * 256 + t;
    if (gi >= n) return;

    const float2 xy = uv[gi];

    // ---------------- hash-grid encoding: 16 levels, 2 feats each ----------
    float feat[32];
    #pragma unroll
    for (int l = 0; l < NLV; l++) {
        const float s = p.scale[l];
        const unsigned res = p.res[l];
        const float px = xy.x * s + 0.5f;
        const float py = xy.y * s + 0.5f;
        const float fpx = floorf(px), fpy = floorf(py);
        const float fx = px - fpx, fy = py - fpy;
        const unsigned x0 = (unsigned)fpx, y0 = (unsigned)fpy;

        unsigned i00, i10, i01, i11;
        if (!((p.hashed_mask >> l) & 1u)) {
            const unsigned b = x0 + y0 * res;
            i00 = b & TMASK;
            i10 = (b + 1u) & TMASK;
            i01 = (b + res) & TMASK;
            i11 = (b + res + 1u) & TMASK;
        } else {
            const unsigned hy0 = y0 * PRIME_Y;
            const unsigned hy1 = (y0 + 1u) * PRIME_Y;
            i00 = (x0 ^ hy0) & TMASK;
            i10 = ((x0 + 1u) ^ hy0) & TMASK;
            i01 = (x0 ^ hy1) & TMASK;
            i11 = ((x0 + 1u) ^ hy1) & TMASK;
        }
        const float2* tl = table + ((size_t)l << LOG2T);
        const float2 c00 = tl[i00];
        const float2 c10 = tl[i10];
        const float2 c01 = tl[i01];
        const float2 c11 = tl[i11];

        const float w00 = (1.f - fx) * (1.f - fy);
        const float w10 = fx * (1.f - fy);
        const float w01 = (1.f - fx) * fy;
        const float w11 = fx * fy;
        feat[2 * l]     = w00 * c00.x + w10 * c10.x + w01 * c01.x + w11 * c11.x;
        feat[2 * l + 1] = w00 * c00.y + w10 * c10.y + w01 * c01.y + w11 * c11.y;
    }

    // ---------------- layer 0: feat[32] @ w0[32,64], relu ------------------
    float2 h0[32];
    #pragma unroll
    for (int j = 0; j < 32; j++) h0[j] = make_float2(0.f, 0.f);
    #pragma unroll
    for (int k = 0; k < 32; k++) {
        const float f = feat[k];
        #pragma unroll
        for (int j = 0; j < 16; j++) {
            const float4 w = sw0[k * 16 + j];
            h0[2 * j].x     = fmaf(f, w.x, h0[2 * j].x);
            h0[2 * j].y     = fmaf(f, w.y, h0[2 * j].y);
            h0[2 * j + 1].x = fmaf(f, w.z, h0[2 * j + 1].x);
            h0[2 * j + 1].y = fmaf(f, w.w, h0[2 * j + 1].y);
        }
    }
    #pragma unroll
    for (int j = 0; j < 32; j++) {
        h0[j].x = fmaxf(h0[j].x, 0.f);
        h0[j].y = fmaxf(h0[j].y, 0.f);
    }

    // ---------------- layer 1: h0[64] @ w1[64,64], relu --------------------
    float2 h1[32];
    #pragma unroll
    for (int j = 0; j < 32; j++) h1[j] = make_float2(0.f, 0.f);
    #pragma unroll
    for (int k = 0; k < 64; k++) {
        const float f = (k & 1) ? h0[k >> 1].y : h0[k >> 1].x;
        #pragma unroll
        for (int j = 0; j < 16; j++) {
            const float4 w = sw1[k * 16 + j];
            h1[2 * j].x     = fmaf(f, w.x, h1[2 * j].x);
            h1[2 * j].y     = fmaf(f, w.y, h1[2 * j].y);
            h1[2 * j + 1].x = fmaf(f, w.z, h1[2 * j + 1].x);
            h1[2 * j + 1].y = fmaf(f, w.w, h1[2 * j + 1].y);
        }
    }
    #pragma unroll
    for (int j = 0; j < 32; j++) {
        h1[j].x = fmaxf(h1[j].x, 0.f);
        h1[j].y = fmaxf(h1[j].y, 0.f);
    }

    // ---------------- layer 2: h1[64] @ w2[64,3], sigmoid ------------------
    float z0 = 0.f, z1 = 0.f, z2 = 0.f;
    #pragma unroll
    for (int k = 0; k < 64; k++) {
        const float f = (k & 1) ? h1[k >> 1].y : h1[k >> 1].x;
        z0 = fmaf(f, sw2[3 * k + 0], z0);
        z1 = fmaf(f, sw2[3 * k + 1], z1);
        z2 = fmaf(f, sw2[3 * k + 2], z2);
    }
    const float o0 = 1.f / (1.f + __expf(-z0));
    const float o1 = 1.f / (1.f + __expf(-z1));
    const float o2 = 1.f / (1.f + __expf(-z2));
    out[3 * gi + 0] = o0;
    out[3 * gi + 1] = o1;
    out[3 * gi + 2] = o2;
}

extern "C" void kernel_launch(void* const* d_in, const int* in_sizes, int n_in,
                              void* d_out, int out_size, void* d_ws, size_t ws_size,
                              hipStream_t stream) {
    const float2* uv    = (const float2*)d_in[0];
    const float2* table = (const float2*)d_in[1];
    const float4* w0    = (const float4*)d_in[2];
    const float4* w1    = (const float4*)d_in[3];
    const float*  w2    = (const float*)d_in[4];
    float* out = (float*)d_out;

    const int n = in_sizes[0] / 2;

    NGPParams p;
    p.hashed_mask = 0;
    const double B = exp((log(2048.0) - log(16.0)) / 15.0);
    for (int l = 0; l < NLV; l++) {
        const double scale = 16.0 * pow(B, (double)l) - 1.0;
        const long long res = (long long)ceil(scale) + 1;
        p.scale[l] = (float)scale;
        p.res[l] = (unsigned)res;
        if (res * res > (long long)TSZ) p.hashed_mask |= (1u << l);
    }

    const int blocks = (n + 255) / 256;
    ngp_fused_kernel<<<blocks, 256, 0, stream>>>(uv, table, w0, w1, w2, out, p, n);
}

// Round 3
// 348.136 us; speedup vs baseline: 1.6601x; 1.6601x over previous
//
#include <hip/hip_runtime.h>
#include <math.h>
#include <stdint.h>

#define NLV 16
#define LOG2T 19
#define TSZ (1u << LOG2T)
#define TMASK (TSZ - 1u)
#define PRIME_Y 2654435761u

struct NGPParams {
    float scale[NLV];
    unsigned res[NLV];
    unsigned hashed_mask;
};

typedef __attribute__((ext_vector_type(8))) short bf16x8;
typedef __attribute__((ext_vector_type(4))) float f32x4;

__device__ inline ushort bf16_rn(float f) {
    uint32_t u = __float_as_uint(f);
    return (ushort)((u + 0x7FFFu + ((u >> 16) & 1u)) >> 16);
}
__device__ inline uint32_t pack_bf16(float a, float b) {
    uint32_t ua = __float_as_uint(a);
    uint32_t ub = __float_as_uint(b);
    uint32_t lo = (ua + 0x7FFFu + ((ua >> 16) & 1u)) >> 16;
    uint32_t hi = (ub + 0x7FFFu + ((ub >> 16) & 1u)) & 0xFFFF0000u;
    return lo | hi;
}

// ======================= K1: level-partitioned encode =======================
// grid = 7 passes * chunks. pass 0 -> levels 0..9 (small tables, L2-resident
// together); pass p>=1 -> level 9+p alone (so its multi-MB table owns L2).
__global__ __launch_bounds__(256) void ngp_encode_kernel(
    const float2* __restrict__ uv,
    const float2* __restrict__ table,
    uint32_t* __restrict__ xt,          // [16][n] packed (bf16 f0 | bf16 f1<<16)
    NGPParams p, int n, int chunks)
{
    const int bid = blockIdx.x;
    const int pass = bid / chunks;
    const int chunk = bid - pass * chunks;
    const int pi = chunk * 256 + threadIdx.x;
    if (pi >= n) return;

    const float2 xy = uv[pi];
    const int l0 = (pass == 0) ? 0 : 9 + pass;
    const int l1 = (pass == 0) ? 9 : 9 + pass;

    for (int l = l0; l <= l1; ++l) {
        const float s = p.scale[l];
        const unsigned res = p.res[l];
        const float px = xy.x * s + 0.5f;
        const float py = xy.y * s + 0.5f;
        const float fpx = floorf(px), fpy = floorf(py);
        const float fx = px - fpx, fy = py - fpy;
        const unsigned x0 = (unsigned)fpx, y0 = (unsigned)fpy;

        unsigned i00, i10, i01, i11;
        if (!((p.hashed_mask >> l) & 1u)) {
            const unsigned b = x0 + y0 * res;
            i00 = b & TMASK;
            i10 = (b + 1u) & TMASK;
            i01 = (b + res) & TMASK;
            i11 = (b + res + 1u) & TMASK;
        } else {
            const unsigned hy0 = y0 * PRIME_Y;
            const unsigned hy1 = (y0 + 1u) * PRIME_Y;
            i00 = (x0 ^ hy0) & TMASK;
            i10 = ((x0 + 1u) ^ hy0) & TMASK;
            i01 = (x0 ^ hy1) & TMASK;
            i11 = ((x0 + 1u) ^ hy1) & TMASK;
        }
        const float2* tl = table + ((size_t)l << LOG2T);
        const float2 c00 = tl[i00];
        const float2 c10 = tl[i10];
        const float2 c01 = tl[i01];
        const float2 c11 = tl[i11];

        const float w00 = (1.f - fx) * (1.f - fy);
        const float w10 = fx * (1.f - fy);
        const float w01 = (1.f - fx) * fy;
        const float w11 = fx * fy;
        const float f0 = w00 * c00.x + w10 * c10.x + w01 * c01.x + w11 * c11.x;
        const float f1 = w00 * c00.y + w10 * c10.y + w01 * c01.y + w11 * c11.y;
        xt[(size_t)l * n + pi] = pack_bf16(f0, f1);
    }
}

// ======================= K2: MFMA fully-fused MLP ==========================
// 256 pts/block, 4 waves, wave w owns M-tiles 4w..4w+3 (rows 64w..64w+63).
// mfma_f32_16x16x32_bf16: A lane(l): row=l&15, k=8*(l>>4)+j ; B: col=l&15,
// k=8*(l>>4)+j ; C/D: col=l&15, row=(l>>4)*4+reg  [measured m89].
__global__ __launch_bounds__(256) void ngp_mlp_kernel(
    const uint32_t* __restrict__ xt,
    const float* __restrict__ w0,       // [32][64] = 2048 floats
    const float* __restrict__ w1,       // [64][64] = 4096 floats
    const float* __restrict__ w2,       // [64][3]  = 192 floats
    float* __restrict__ out, int n)
{
    __shared__ __align__(16) uint32_t Xl[16 * 256];     // [level][pt] 16 KB
    __shared__ __align__(16) ushort  W0T[64 * 72];      // [n][k] stride 72
    __shared__ __align__(16) ushort  W1T[64 * 72];      // [n][k] stride 72
    __shared__ __align__(16) ushort  W2T[16 * 72];      // [n][k] stride 72
    __shared__ __align__(16) ushort  H[256 * 72];       // [p][k] stride 72

    const int t = threadIdx.x;
    const int lane = t & 63;
    const int w = t >> 6;
    const int p0 = blockIdx.x * 256;

    // --- async stage X: 16 segs of 1KB (one level row each) ---
    #pragma unroll
    for (int i = 0; i < 4; ++i) {
        const int seg = i * 4 + w;                      // level index
        int pp = p0 + (lane << 2);                      // 4 pts per lane
        if (pp + 4 > n) pp = (n >= 4) ? n - 4 : 0;      // tail clamp
        const uint32_t* g = xt + (size_t)seg * n + pp;
        uint32_t* lb = &Xl[seg * 256];                  // wave-uniform base
        __builtin_amdgcn_global_load_lds(
            (const __attribute__((address_space(1))) uint32_t*)g,
            (__attribute__((address_space(3))) uint32_t*)lb, 16, 0, 0);
    }

    // --- stage weights transposed to bf16 (single writer per slot) ---
    #pragma unroll
    for (int i = 0; i < 8; ++i) {
        int idx = t + 256 * i;                          // 0..2047  (32x64)
        int k = idx >> 6, nn = idx & 63;
        W0T[nn * 72 + k] = bf16_rn(w0[idx]);
    }
    #pragma unroll
    for (int i = 0; i < 16; ++i) {
        int idx = t + 256 * i;                          // 0..4095  (64x64)
        int k = idx >> 6, nn = idx & 63;
        W1T[nn * 72 + k] = bf16_rn(w1[idx]);
    }
    #pragma unroll
    for (int i = 0; i < 4; ++i) {
        int idx = t + 256 * i;                          // 0..1023  (16x64 padded)
        int nn = idx >> 6, k = idx & 63;
        W2T[nn * 72 + k] = (nn < 3) ? bf16_rn(w2[k * 3 + nn]) : (ushort)0;
    }

    __syncthreads();   // drains global_load_lds (vmcnt) + ds writes

    const int g4 = lane >> 4;       // 0..3
    const int r16 = lane & 15;

    // ---------------- layer 0: X[256x32] @ W0[32x64] -----------------------
    f32x4 acc[4][4];
    #pragma unroll
    for (int mi = 0; mi < 4; ++mi)
        #pragma unroll
        for (int nt = 0; nt < 4; ++nt)
            acc[mi][nt] = (f32x4){0.f, 0.f, 0.f, 0.f};

    bf16x8 a0[4];
    #pragma unroll
    for (int mi = 0; mi < 4; ++mi) {
        const int pl = (w * 4 + mi) * 16 + r16;
        union { uint32_t u[4]; bf16x8 v; } cv;
        #pragma unroll
        for (int c = 0; c < 4; ++c)
            cv.u[c] = Xl[(4 * g4 + c) * 256 + pl];      // dword = (k,k+1), k=8g+2c
        a0[mi] = cv.v;
    }
    bf16x8 b0[4];
    #pragma unroll
    for (int nt = 0; nt < 4; ++nt)
        b0[nt] = *(const bf16x8*)&W0T[(nt * 16 + r16) * 72 + 8 * g4];

    #pragma unroll
    for (int mi = 0; mi < 4; ++mi)
        #pragma unroll
        for (int nt = 0; nt < 4; ++nt)
            acc[mi][nt] = __builtin_amdgcn_mfma_f32_16x16x32_bf16(a0[mi], b0[nt], acc[mi][nt], 0, 0, 0);

    #pragma unroll
    for (int mi = 0; mi < 4; ++mi)
        #pragma unroll
        for (int nt = 0; nt < 4; ++nt)
            #pragma unroll
            for (int r = 0; r < 4; ++r) {
                const int pl = (w * 4 + mi) * 16 + g4 * 4 + r;
                H[pl * 72 + nt * 16 + r16] = bf16_rn(fmaxf(acc[mi][nt][r], 0.f));
            }
    // no barrier: each wave's H rows are private to the wave.

    // ---------------- layer 1: H0[256x64] @ W1[64x64] ----------------------
    bf16x8 a1[4][2], b1[4][2];
    #pragma unroll
    for (int mi = 0; mi < 4; ++mi) {
        const int pl = (w * 4 + mi) * 16 + r16;
        a1[mi][0] = *(const bf16x8*)&H[pl * 72 + 8 * g4];
        a1[mi][1] = *(const bf16x8*)&H[pl * 72 + 32 + 8 * g4];
    }
    #pragma unroll
    for (int nt = 0; nt < 4; ++nt) {
        const int nn = nt * 16 + r16;
        b1[nt][0] = *(const bf16x8*)&W1T[nn * 72 + 8 * g4];
        b1[nt][1] = *(const bf16x8*)&W1T[nn * 72 + 32 + 8 * g4];
    }
    #pragma unroll
    for (int mi = 0; mi < 4; ++mi)
        #pragma unroll
        for (int nt = 0; nt < 4; ++nt) {
            acc[mi][nt] = (f32x4){0.f, 0.f, 0.f, 0.f};
            acc[mi][nt] = __builtin_amdgcn_mfma_f32_16x16x32_bf16(a1[mi][0], b1[nt][0], acc[mi][nt], 0, 0, 0);
            acc[mi][nt] = __builtin_amdgcn_mfma_f32_16x16x32_bf16(a1[mi][1], b1[nt][1], acc[mi][nt], 0, 0, 0);
        }
    #pragma unroll
    for (int mi = 0; mi < 4; ++mi)
        #pragma unroll
        for (int nt = 0; nt < 4; ++nt)
            #pragma unroll
            for (int r = 0; r < 4; ++r) {
                const int pl = (w * 4 + mi) * 16 + g4 * 4 + r;
                H[pl * 72 + nt * 16 + r16] = bf16_rn(fmaxf(acc[mi][nt][r], 0.f));
            }

    // ---------------- layer 2: H1[256x64] @ W2pad[64x16] -------------------
    bf16x8 a2[2], b2[2];
    b2[0] = *(const bf16x8*)&W2T[r16 * 72 + 8 * g4];
    b2[1] = *(const bf16x8*)&W2T[r16 * 72 + 32 + 8 * g4];
    const int c = r16;
    #pragma unroll
    for (int mi = 0; mi < 4; ++mi) {
        const int pl = (w * 4 + mi) * 16 + r16;
        a2[0] = *(const bf16x8*)&H[pl * 72 + 8 * g4];
        a2[1] = *(const bf16x8*)&H[pl * 72 + 32 + 8 * g4];
        f32x4 z = (f32x4){0.f, 0.f, 0.f, 0.f};
        z = __builtin_amdgcn_mfma_f32_16x16x32_bf16(a2[0], b2[0], z, 0, 0, 0);
        z = __builtin_amdgcn_mfma_f32_16x16x32_bf16(a2[1], b2[1], z, 0, 0, 0);
        if (c < 3) {
            #pragma unroll
            for (int r = 0; r < 4; ++r) {
                const int pg = p0 + (w * 4 + mi) * 16 + g4 * 4 + r;
                if (pg < n)
                    out[(size_t)pg * 3 + c] = 1.f / (1.f + __expf(-z[r]));
            }
        }
    }
}

// ======================= fallback: round-1 fused kernel ====================
__global__ __launch_bounds__(256) void ngp_fused_kernel(
    const float2* __restrict__ uv,
    const float2* __restrict__ table,
    const float4* __restrict__ w0,
    const float4* __restrict__ w1,
    const float*  __restrict__ w2,
    float* __restrict__ out,
    NGPParams p, int n)
{
    __shared__ float4 sw0[512];
    __shared__ float4 sw1[1024];
    __shared__ float  sw2[192];
    const int t = threadIdx.x;
    #pragma unroll
    for (int i = 0; i < 2; i++) sw0[t + 256 * i] = w0[t + 256 * i];
    #pragma unroll
    for (int i = 0; i < 4; i++) sw1[t + 256 * i] = w1[t + 256 * i];
    if (t < 192) sw2[t] = w2[t];
    __syncthreads();
    const int gi = blockIdx.x * 256 + t;
    if (gi >= n) return;
    const float2 xy = uv[gi];
    float feat[32];
    #pragma unroll
    for (int l = 0; l < NLV; l++) {
        const float s = p.scale[l];
        const unsigned res = p.res[l];
        const float px = xy.x * s + 0.5f;
        const float py = xy.y * s + 0.5f;
        const float fpx = floorf(px), fpy = floorf(py);
        const float fx = px - fpx, fy = py - fpy;
        const unsigned x0 = (unsigned)fpx, y0 = (unsigned)fpy;
        unsigned i00, i10, i01, i11;
        if (!((p.hashed_mask >> l) & 1u)) {
            const unsigned b = x0 + y0 * res;
            i00 = b & TMASK; i10 = (b + 1u) & TMASK;
            i01 = (b + res) & TMASK; i11 = (b + res + 1u) & TMASK;
        } else {
            const unsigned hy0 = y0 * PRIME_Y;
            const unsigned hy1 = (y0 + 1u) * PRIME_Y;
            i00 = (x0 ^ hy0) & TMASK; i10 = ((x0 + 1u) ^ hy0) & TMASK;
            i01 = (x0 ^ hy1) & TMASK; i11 = ((x0 + 1u) ^ hy1) & TMASK;
        }
        const float2* tl = table + ((size_t)l << LOG2T);
        const float2 c00 = tl[i00], c10 = tl[i10], c01 = tl[i01], c11 = tl[i11];
        const float w00 = (1.f - fx) * (1.f - fy);
        const float w10 = fx * (1.f - fy);
        const float w01 = (1.f - fx) * fy;
        const float w11 = fx * fy;
        feat[2 * l]     = w00 * c00.x + w10 * c10.x + w01 * c01.x + w11 * c11.x;
        feat[2 * l + 1] = w00 * c00.y + w10 * c10.y + w01 * c01.y + w11 * c11.y;
    }
    float2 h0[32];
    #pragma unroll
    for (int j = 0; j < 32; j++) h0[j] = make_float2(0.f, 0.f);
    #pragma unroll
    for (int k = 0; k < 32; k++) {
        const float f = feat[k];
        #pragma unroll
        for (int j = 0; j < 16; j++) {
            const float4 ww = sw0[k * 16 + j];
            h0[2 * j].x = fmaf(f, ww.x, h0[2 * j].x);
            h0[2 * j].y = fmaf(f, ww.y, h0[2 * j].y);
            h0[2 * j + 1].x = fmaf(f, ww.z, h0[2 * j + 1].x);
            h0[2 * j + 1].y = fmaf(f, ww.w, h0[2 * j + 1].y);
        }
    }
    #pragma unroll
    for (int j = 0; j < 32; j++) {
        h0[j].x = fmaxf(h0[j].x, 0.f);
        h0[j].y = fmaxf(h0[j].y, 0.f);
    }
    float2 h1[32];
    #pragma unroll
    for (int j = 0; j < 32; j++) h1[j] = make_float2(0.f, 0.f);
    #pragma unroll
    for (int k = 0; k < 64; k++) {
        const float f = (k & 1) ? h0[k >> 1].y : h0[k >> 1].x;
        #pragma unroll
        for (int j = 0; j < 16; j++) {
            const float4 ww = sw1[k * 16 + j];
            h1[2 * j].x = fmaf(f, ww.x, h1[2 * j].x);
            h1[2 * j].y = fmaf(f, ww.y, h1[2 * j].y);
            h1[2 * j + 1].x = fmaf(f, ww.z, h1[2 * j + 1].x);
            h1[2 * j + 1].y = fmaf(f, ww.w, h1[2 * j + 1].y);
        }
    }
    #pragma unroll
    for (int j = 0; j < 32; j++) {
        h1[j].x = fmaxf(h1[j].x, 0.f);
        h1[j].y = fmaxf(h1[j].y, 0.f);
    }
    float z0 = 0.f, z1 = 0.f, z2 = 0.f;
    #pragma unroll
    for (int k = 0; k < 64; k++) {
        const float f = (k & 1) ? h1[k >> 1].y : h1[k >> 1].x;
        z0 = fmaf(f, sw2[3 * k + 0], z0);
        z1 = fmaf(f, sw2[3 * k + 1], z1);
        z2 = fmaf(f, sw2[3 * k + 2], z2);
    }
    out[3 * gi + 0] = 1.f / (1.f + __expf(-z0));
    out[3 * gi + 1] = 1.f / (1.f + __expf(-z1));
    out[3 * gi + 2] = 1.f / (1.f + __expf(-z2));
}

extern "C" void kernel_launch(void* const* d_in, const int* in_sizes, int n_in,
                              void* d_out, int out_size, void* d_ws, size_t ws_size,
                              hipStream_t stream) {
    const float2* uv    = (const float2*)d_in[0];
    const float2* table = (const float2*)d_in[1];
    const float*  w0f   = (const float*)d_in[2];
    const float*  w1f   = (const float*)d_in[3];
    const float*  w2f   = (const float*)d_in[4];
    float* out = (float*)d_out;

    const int n = in_sizes[0] / 2;

    NGPParams p;
    p.hashed_mask = 0;
    const double B = exp((log(2048.0) - log(16.0)) / 15.0);
    for (int l = 0; l < NLV; l++) {
        const double scale = 16.0 * pow(B, (double)l) - 1.0;
        const long long res = (long long)ceil(scale) + 1;
        p.scale[l] = (float)scale;
        p.res[l] = (unsigned)res;
        if (res * res > (long long)TSZ) p.hashed_mask |= (1u << l);
    }

    const size_t need = (size_t)NLV * (size_t)n * 4u;
    const int chunks = (n + 255) / 256;

    if (ws_size < need) {   // fallback: verified round-1 fused kernel
        ngp_fused_kernel<<<chunks, 256, 0, stream>>>(
            uv, table, (const float4*)w0f, (const float4*)w1f, w2f, out, p, n);
        return;
    }

    uint32_t* xt = (uint32_t*)d_ws;
    ngp_encode_kernel<<<7 * chunks, 256, 0, stream>>>(uv, table, xt, p, n, chunks);
    ngp_mlp_kernel<<<chunks, 256, 0, stream>>>(xt, w0f, w1f, w2f, out, n);
}

// Round 4
// 344.044 us; speedup vs baseline: 1.6798x; 1.0119x over previous
//
#include <hip/hip_runtime.h>
#include <math.h>
#include <stdint.h>

#define NLV 16
#define LOG2T 19
#define TSZ (1u << LOG2T)
#define TMASK (TSZ - 1u)
#define PRIME_Y 2654435761u

// weight-pack layout (ushorts): W0T[64][72] | W1T[64][72] | W2T[16][72]
#define W0OFF 0
#define W1OFF 4608
#define W2OFF 9216
#define WPTOT 10368          // ushorts = 20736 B = 1296 uint4

struct NGPParams {
    float scale[NLV];
    unsigned res[NLV];
    unsigned hashed_mask;
};

typedef __attribute__((ext_vector_type(8))) short bf16x8;
typedef __attribute__((ext_vector_type(4))) float f32x4;

__device__ inline ushort bf16_rn(float f) {
    uint32_t u = __float_as_uint(f);
    return (ushort)((u + 0x7FFFu + ((u >> 16) & 1u)) >> 16);
}
__device__ inline uint32_t pack_bf16(float a, float b) {
    uint32_t ua = __float_as_uint(a);
    uint32_t ub = __float_as_uint(b);
    uint32_t lo = (ua + 0x7FFFu + ((ua >> 16) & 1u)) >> 16;
    uint32_t hi = (ub + 0x7FFFu + ((ub >> 16) & 1u)) & 0xFFFF0000u;
    return lo | hi;
}

// ======================= K0: one-time weight prep ==========================
__global__ __launch_bounds__(256) void ngp_prep_weights(
    const float* __restrict__ w0, const float* __restrict__ w1,
    const float* __restrict__ w2, ushort* __restrict__ wp)
{
    const int t = threadIdx.x;
    #pragma unroll
    for (int i = 0; i < 8; ++i) {            // w0: 32x64
        int idx = t + 256 * i;
        int k = idx >> 6, nn = idx & 63;
        wp[W0OFF + nn * 72 + k] = bf16_rn(w0[idx]);
    }
    #pragma unroll
    for (int i = 0; i < 16; ++i) {           // w1: 64x64
        int idx = t + 256 * i;
        int k = idx >> 6, nn = idx & 63;
        wp[W1OFF + nn * 72 + k] = bf16_rn(w1[idx]);
    }
    #pragma unroll
    for (int i = 0; i < 4; ++i) {            // w2: 64x3 -> padded 16x64
        int idx = t + 256 * i;
        int nn = idx >> 6, k = idx & 63;
        wp[W2OFF + nn * 72 + k] = (nn < 3) ? bf16_rn(w2[k * 3 + nn]) : (ushort)0;
    }
}

// ======================= K1: level-partitioned encode, 4 pts/thread ========
// grid = 7 passes * chunks4. pass 0 -> levels 0..9 (tables sum ~1.5 MB,
// L2-resident together); pass p>=1 -> level 9+p alone (multi-MB table owns
// L2). Each thread handles 4 points -> 16 gathers in flight per level.
__global__ __launch_bounds__(256) void ngp_encode4_kernel(
    const float2* __restrict__ uv,
    const float2* __restrict__ table,
    uint32_t* __restrict__ xt,          // [16][n] packed (bf16 f0 | bf16 f1<<16)
    NGPParams p, int n, int chunks4)
{
    const int bid = blockIdx.x;
    const int pass = bid / chunks4;
    const int chunk = bid - pass * chunks4;
    const int base = chunk * 1024 + threadIdx.x;

    float2 xy[4];
    #pragma unroll
    for (int q = 0; q < 4; ++q) {
        const int idx = base + q * 256;
        xy[q] = uv[idx < n ? idx : 0];
    }

    const int l0 = (pass == 0) ? 0 : 9 + pass;
    const int l1 = (pass == 0) ? 9 : 9 + pass;

    for (int l = l0; l <= l1; ++l) {
        const float s = p.scale[l];
        const unsigned res = p.res[l];
        const bool hashed = (p.hashed_mask >> l) & 1u;
        const float2* tl = table + ((size_t)l << LOG2T);

        float fx[4], fy[4];
        unsigned ind[4][4];
        #pragma unroll
        for (int q = 0; q < 4; ++q) {
            const float px = xy[q].x * s + 0.5f;
            const float py = xy[q].y * s + 0.5f;
            const float fpx = floorf(px), fpy = floorf(py);
            fx[q] = px - fpx; fy[q] = py - fpy;
            const unsigned x0 = (unsigned)fpx, y0 = (unsigned)fpy;
            if (!hashed) {
                const unsigned b = x0 + y0 * res;
                ind[q][0] = b & TMASK;
                ind[q][1] = (b + 1u) & TMASK;
                ind[q][2] = (b + res) & TMASK;
                ind[q][3] = (b + res + 1u) & TMASK;
            } else {
                const unsigned hy0 = y0 * PRIME_Y;
                const unsigned hy1 = (y0 + 1u) * PRIME_Y;
                ind[q][0] = (x0 ^ hy0) & TMASK;
                ind[q][1] = ((x0 + 1u) ^ hy0) & TMASK;
                ind[q][2] = (x0 ^ hy1) & TMASK;
                ind[q][3] = ((x0 + 1u) ^ hy1) & TMASK;
            }
        }
        float2 c[4][4];
        #pragma unroll
        for (int q = 0; q < 4; ++q)
            #pragma unroll
            for (int j = 0; j < 4; ++j)
                c[q][j] = tl[ind[q][j]];         // 16 independent gathers

        #pragma unroll
        for (int q = 0; q < 4; ++q) {
            const float w00 = (1.f - fx[q]) * (1.f - fy[q]);
            const float w10 = fx[q] * (1.f - fy[q]);
            const float w01 = (1.f - fx[q]) * fy[q];
            const float w11 = fx[q] * fy[q];
            const float f0 = w00 * c[q][0].x + w10 * c[q][1].x + w01 * c[q][2].x + w11 * c[q][3].x;
            const float f1 = w00 * c[q][0].y + w10 * c[q][1].y + w01 * c[q][2].y + w11 * c[q][3].y;
            const int idx = base + q * 256;
            if (idx < n) xt[(size_t)l * n + idx] = pack_bf16(f0, f1);
        }
    }
}

// ======================= K2: MFMA fully-fused MLP ==========================
// 256 pts/block, 4 waves, wave w owns M-tiles 4w..4w+3 (rows 64w..64w+63).
// mfma_f32_16x16x32_bf16: A lane(l): row=l&15, k=8*(l>>4)+j ; B: col=l&15,
// k=8*(l>>4)+j ; C/D: col=l&15, row=(l>>4)*4+reg  [measured m89].
__global__ __launch_bounds__(256) void ngp_mlp_kernel(
    const uint32_t* __restrict__ xt,
    const ushort* __restrict__ wp,      // prepped bf16 weight pack
    float* __restrict__ out, int n)
{
    __shared__ __align__(16) uint32_t Xl[16 * 256];     // [level][pt] 16 KB
    __shared__ __align__(16) ushort  WP[WPTOT];         // 20.7 KB
    __shared__ __align__(16) ushort  H[256 * 72];       // [p][k] stride 72

    const int t = threadIdx.x;
    const int lane = t & 63;
    const int w = t >> 6;
    const int p0 = blockIdx.x * 256;

    // --- async stage X: 16 segs of 1KB (one level row each) ---
    #pragma unroll
    for (int i = 0; i < 4; ++i) {
        const int seg = i * 4 + w;                      // level index
        int pp = p0 + (lane << 2);                      // 4 pts per lane
        if (pp + 4 > n) pp = (n >= 4) ? n - 4 : 0;      // tail clamp
        const uint32_t* g = xt + (size_t)seg * n + pp;
        uint32_t* lb = &Xl[seg * 256];                  // wave-uniform base
        __builtin_amdgcn_global_load_lds(
            (const __attribute__((address_space(1))) uint32_t*)g,
            (__attribute__((address_space(3))) uint32_t*)lb, 16, 0, 0);
    }

    // --- copy prepped weights (no conversion) ---
    {
        const uint4* gsrc = (const uint4*)wp;
        uint4* sdst = (uint4*)WP;
        #pragma unroll
        for (int i = 0; i < 6; ++i) {
            const int idx = t + 256 * i;
            if (idx < WPTOT / 8) sdst[idx] = gsrc[idx];
        }
    }

    __syncthreads();   // drains global_load_lds (vmcnt) + ds writes

    const ushort* W0T = WP + W0OFF;
    const ushort* W1T = WP + W1OFF;
    const ushort* W2T = WP + W2OFF;

    const int g4 = lane >> 4;       // 0..3
    const int r16 = lane & 15;

    // ---------------- layer 0: X[256x32] @ W0[32x64] -----------------------
    f32x4 acc[4][4];
    #pragma unroll
    for (int mi = 0; mi < 4; ++mi)
        #pragma unroll
        for (int nt = 0; nt < 4; ++nt)
            acc[mi][nt] = (f32x4){0.f, 0.f, 0.f, 0.f};

    bf16x8 a0[4];
    #pragma unroll
    for (int mi = 0; mi < 4; ++mi) {
        const int pl = (w * 4 + mi) * 16 + r16;
        union { uint32_t u[4]; bf16x8 v; } cv;
        #pragma unroll
        for (int c = 0; c < 4; ++c)
            cv.u[c] = Xl[(4 * g4 + c) * 256 + pl];      // dword = (k,k+1), k=8g+2c
        a0[mi] = cv.v;
    }
    bf16x8 b0[4];
    #pragma unroll
    for (int nt = 0; nt < 4; ++nt)
        b0[nt] = *(const bf16x8*)&W0T[(nt * 16 + r16) * 72 + 8 * g4];

    #pragma unroll
    for (int mi = 0; mi < 4; ++mi)
        #pragma unroll
        for (int nt = 0; nt < 4; ++nt)
            acc[mi][nt] = __builtin_amdgcn_mfma_f32_16x16x32_bf16(a0[mi], b0[nt], acc[mi][nt], 0, 0, 0);

    #pragma unroll
    for (int mi = 0; mi < 4; ++mi)
        #pragma unroll
        for (int nt = 0; nt < 4; ++nt)
            #pragma unroll
            for (int r = 0; r < 4; ++r) {
                const int pl = (w * 4 + mi) * 16 + g4 * 4 + r;
                H[pl * 72 + nt * 16 + r16] = bf16_rn(fmaxf(acc[mi][nt][r], 0.f));
            }
    // no barrier: each wave's H rows are private to the wave.

    // ---------------- layer 1: H0[256x64] @ W1[64x64] ----------------------
    bf16x8 a1[4][2], b1[4][2];
    #pragma unroll
    for (int mi = 0; mi < 4; ++mi) {
        const int pl = (w * 4 + mi) * 16 + r16;
        a1[mi][0] = *(const bf16x8*)&H[pl * 72 + 8 * g4];
        a1[mi][1] = *(const bf16x8*)&H[pl * 72 + 32 + 8 * g4];
    }
    #pragma unroll
    for (int nt = 0; nt < 4; ++nt) {
        const int nn = nt * 16 + r16;
        b1[nt][0] = *(const bf16x8*)&W1T[nn * 72 + 8 * g4];
        b1[nt][1] = *(const bf16x8*)&W1T[nn * 72 + 32 + 8 * g4];
    }
    #pragma unroll
    for (int mi = 0; mi < 4; ++mi)
        #pragma unroll
        for (int nt = 0; nt < 4; ++nt) {
            acc[mi][nt] = (f32x4){0.f, 0.f, 0.f, 0.f};
            acc[mi][nt] = __builtin_amdgcn_mfma_f32_16x16x32_bf16(a1[mi][0], b1[nt][0], acc[mi][nt], 0, 0, 0);
            acc[mi][nt] = __builtin_amdgcn_mfma_f32_16x16x32_bf16(a1[mi][1], b1[nt][1], acc[mi][nt], 0, 0, 0);
        }
    #pragma unroll
    for (int mi = 0; mi < 4; ++mi)
        #pragma unroll
        for (int nt = 0; nt < 4; ++nt)
            #pragma unroll
            for (int r = 0; r < 4; ++r) {
                const int pl = (w * 4 + mi) * 16 + g4 * 4 + r;
                H[pl * 72 + nt * 16 + r16] = bf16_rn(fmaxf(acc[mi][nt][r], 0.f));
            }

    // ---------------- layer 2: H1[256x64] @ W2pad[64x16] -------------------
    bf16x8 a2[2], b2[2];
    b2[0] = *(const bf16x8*)&W2T[r16 * 72 + 8 * g4];
    b2[1] = *(const bf16x8*)&W2T[r16 * 72 + 32 + 8 * g4];
    const int c = r16;
    #pragma unroll
    for (int mi = 0; mi < 4; ++mi) {
        const int pl = (w * 4 + mi) * 16 + r16;
        a2[0] = *(const bf16x8*)&H[pl * 72 + 8 * g4];
        a2[1] = *(const bf16x8*)&H[pl * 72 + 32 + 8 * g4];
        f32x4 z = (f32x4){0.f, 0.f, 0.f, 0.f};
        z = __builtin_amdgcn_mfma_f32_16x16x32_bf16(a2[0], b2[0], z, 0, 0, 0);
        z = __builtin_amdgcn_mfma_f32_16x16x32_bf16(a2[1], b2[1], z, 0, 0, 0);
        if (c < 3) {
            #pragma unroll
            for (int r = 0; r < 4; ++r) {
                const int pg = p0 + (w * 4 + mi) * 16 + g4 * 4 + r;
                if (pg < n)
                    out[(size_t)pg * 3 + c] = 1.f / (1.f + __expf(-z[r]));
            }
        }
    }
}

// ======================= fallback: round-1 fused kernel ====================
__global__ __launch_bounds__(256) void ngp_fused_kernel(
    const float2* __restrict__ uv,
    const float2* __restrict__ table,
    const float4* __restrict__ w0,
    const float4* __restrict__ w1,
    const float*  __restrict__ w2,
    float* __restrict__ out,
    NGPParams p, int n)
{
    __shared__ float4 sw0[512];
    __shared__ float4 sw1[1024];
    __shared__ float  sw2[192];
    const int t = threadIdx.x;
    #pragma unroll
    for (int i = 0; i < 2; i++) sw0[t + 256 * i] = w0[t + 256 * i];
    #pragma unroll
    for (int i = 0; i < 4; i++) sw1[t + 256 * i] = w1[t + 256 * i];
    if (t < 192) sw2[t] = w2[t];
    __syncthreads();
    const int gi = blockIdx.x * 256 + t;
    if (gi >= n) return;
    const float2 xy = uv[gi];
    float feat[32];
    #pragma unroll
    for (int l = 0; l < NLV; l++) {
        const float s = p.scale[l];
        const unsigned res = p.res[l];
        const float px = xy.x * s + 0.5f;
        const float py = xy.y * s + 0.5f;
        const float fpx = floorf(px), fpy = floorf(py);
        const float fx = px - fpx, fy = py - fpy;
        const unsigned x0 = (unsigned)fpx, y0 = (unsigned)fpy;
        unsigned i00, i10, i01, i11;
        if (!((p.hashed_mask >> l) & 1u)) {
            const unsigned b = x0 + y0 * res;
            i00 = b & TMASK; i10 = (b + 1u) & TMASK;
            i01 = (b + res) & TMASK; i11 = (b + res + 1u) & TMASK;
        } else {
            const unsigned hy0 = y0 * PRIME_Y;
            const unsigned hy1 = (y0 + 1u) * PRIME_Y;
            i00 = (x0 ^ hy0) & TMASK; i10 = ((x0 + 1u) ^ hy0) & TMASK;
            i01 = (x0 ^ hy1) & TMASK; i11 = ((x0 + 1u) ^ hy1) & TMASK;
        }
        const float2* tl = table + ((size_t)l << LOG2T);
        const float2 c00 = tl[i00], c10 = tl[i10], c01 = tl[i01], c11 = tl[i11];
        const float w00 = (1.f - fx) * (1.f - fy);
        const float w10 = fx * (1.f - fy);
        const float w01 = (1.f - fx) * fy;
        const float w11 = fx * fy;
        feat[2 * l]     = w00 * c00.x + w10 * c10.x + w01 * c01.x + w11 * c11.x;
        feat[2 * l + 1] = w00 * c00.y + w10 * c10.y + w01 * c01.y + w11 * c11.y;
    }
    float2 h0[32];
    #pragma unroll
    for (int j = 0; j < 32; j++) h0[j] = make_float2(0.f, 0.f);
    #pragma unroll
    for (int k = 0; k < 32; k++) {
        const float f = feat[k];
        #pragma unroll
        for (int j = 0; j < 16; j++) {
            const float4 ww = sw0[k * 16 + j];
            h0[2 * j].x = fmaf(f, ww.x, h0[2 * j].x);
            h0[2 * j].y = fmaf(f, ww.y, h0[2 * j].y);
            h0[2 * j + 1].x = fmaf(f, ww.z, h0[2 * j + 1].x);
            h0[2 * j + 1].y = fmaf(f, ww.w, h0[2 * j + 1].y);
        }
    }
    #pragma unroll
    for (int j = 0; j < 32; j++) {
        h0[j].x = fmaxf(h0[j].x, 0.f);
        h0[j].y = fmaxf(h0[j].y, 0.f);
    }
    float2 h1[32];
    #pragma unroll
    for (int j = 0; j < 32; j++) h1[j] = make_float2(0.f, 0.f);
    #pragma unroll
    for (int k = 0; k < 64; k++) {
        const float f = (k & 1) ? h0[k >> 1].y : h0[k >> 1].x;
        #pragma unroll
        for (int j = 0; j < 16; j++) {
            const float4 ww = sw1[k * 16 + j];
            h1[2 * j].x = fmaf(f, ww.x, h1[2 * j].x);
            h1[2 * j].y = fmaf(f, ww.y, h1[2 * j].y);
            h1[2 * j + 1].x = fmaf(f, ww.z, h1[2 * j + 1].x);
            h1[2 * j + 1].y = fmaf(f, ww.w, h1[2 * j + 1].y);
        }
    }
    #pragma unroll
    for (int j = 0; j < 32; j++) {
        h1[j].x = fmaxf(h1[j].x, 0.f);
        h1[j].y = fmaxf(h1[j].y, 0.f);
    }
    float z0 = 0.f, z1 = 0.f, z2 = 0.f;
    #pragma unroll
    for (int k = 0; k < 64; k++) {
        const float f = (k & 1) ? h1[k >> 1].y : h1[k >> 1].x;
        z0 = fmaf(f, sw2[3 * k + 0], z0);
        z1 = fmaf(f, sw2[3 * k + 1], z1);
        z2 = fmaf(f, sw2[3 * k + 2], z2);
    }
    out[3 * gi + 0] = 1.f / (1.f + __expf(-z0));
    out[3 * gi + 1] = 1.f / (1.f + __expf(-z1));
    out[3 * gi + 2] = 1.f / (1.f + __expf(-z2));
}

extern "C" void kernel_launch(void* const* d_in, const int* in_sizes, int n_in,
                              void* d_out, int out_size, void* d_ws, size_t ws_size,
                              hipStream_t stream) {
    const float2* uv    = (const float2*)d_in[0];
    const float2* table = (const float2*)d_in[1];
    const float*  w0f   = (const float*)d_in[2];
    const float*  w1f   = (const float*)d_in[3];
    const float*  w2f   = (const float*)d_in[4];
    float* out = (float*)d_out;

    const int n = in_sizes[0] / 2;

    NGPParams p;
    p.hashed_mask = 0;
    const double B = exp((log(2048.0) - log(16.0)) / 15.0);
    for (int l = 0; l < NLV; l++) {
        const double scale = 16.0 * pow(B, (double)l) - 1.0;
        const long long res = (long long)ceil(scale) + 1;
        p.scale[l] = (float)scale;
        p.res[l] = (unsigned)res;
        if (res * res > (long long)TSZ) p.hashed_mask |= (1u << l);
    }

    const size_t xt_bytes = (size_t)NLV * (size_t)n * 4u;
    const size_t need = xt_bytes + WPTOT * 2u;
    const int chunks = (n + 255) / 256;

    if (ws_size < need) {   // fallback: verified round-1 fused kernel
        ngp_fused_kernel<<<chunks, 256, 0, stream>>>(
            uv, table, (const float4*)w0f, (const float4*)w1f, w2f, out, p, n);
        return;
    }

    uint32_t* xt = (uint32_t*)d_ws;
    ushort* wp = (ushort*)((char*)d_ws + xt_bytes);

    ngp_prep_weights<<<1, 256, 0, stream>>>(w0f, w1f, w2f, wp);
    const int chunks4 = (n + 1023) / 1024;
    ngp_encode4_kernel<<<7 * chunks4, 256, 0, stream>>>(uv, table, xt, p, n, chunks4);
    ngp_mlp_kernel<<<chunks, 256, 0, stream>>>(xt, wp, out, n);
}

// Round 5
// 296.558 us; speedup vs baseline: 1.9488x; 1.1601x over previous
//
#include <hip/hip_runtime.h>
#include <math.h>
#include <stdint.h>

#define NLV 16
#define LOG2T 19
#define TSZ (1u << LOG2T)
#define TMASK (TSZ - 1u)
#define PRIME_Y 2654435761u

// frag-major weight pack: 14 frags x 64 lanes x 8 bf16 = 14336 B
// f 0..3  : W0 A-frags, n = f*16 + r16, k = 8*g4 + j           (K=32)
// f 4..11 : W1 A-frags, q=f-4: n = (q>>1)*16 + r16, k = (q&1)*32 + 8*g4 + j
// f 12..13: W2 A-frags, n = r16 (pad>=3 -> 0), k = (f-12)*32 + 8*g4 + j
#define NFRAG 14
#define WPF_USHORTS (NFRAG * 64 * 8)

struct NGPParams {
    float scale[NLV];
    unsigned res[NLV];
    unsigned hashed_mask;
};

struct __align__(8) pairld { float x, y, z, w; };   // 16B, 8B-aligned load

typedef __attribute__((ext_vector_type(8))) short bf16x8;
typedef __attribute__((ext_vector_type(4))) float f32x4;

__device__ inline ushort bf16_rn(float f) {
    uint32_t u = __float_as_uint(f);
    return (ushort)((u + 0x7FFFu + ((u >> 16) & 1u)) >> 16);
}
__device__ inline uint32_t pack_bf16(float a, float b) {
    uint32_t ua = __float_as_uint(a);
    uint32_t ub = __float_as_uint(b);
    uint32_t lo = (ua + 0x7FFFu + ((ua >> 16) & 1u)) >> 16;
    uint32_t hi = (ub + 0x7FFFu + ((ub >> 16) & 1u)) & 0xFFFF0000u;
    return lo | hi;
}
// (hi16(a) << 16) | hi16(b)  == packed bf16 truncation of two f32
__device__ inline uint32_t pack_trunc(float a, float b) {
    return __builtin_amdgcn_perm(__float_as_uint(a), __float_as_uint(b), 0x07060302u);
}

// ======================= K0: one-time frag-major weight prep ===============
__global__ __launch_bounds__(256) void ngp_prep_wfrag(
    const float* __restrict__ w0, const float* __restrict__ w1,
    const float* __restrict__ w2, ushort* __restrict__ wpf)
{
    const int t = threadIdx.x;
    for (int i = 0; i < 4; ++i) {
        const int e = t + 256 * i;
        if (e >= NFRAG * 64) continue;
        const int f = e >> 6, lane = e & 63;
        const int g4 = lane >> 4, r16 = lane & 15;
        ushort v[8];
        if (f < 4) {
            const int n = f * 16 + r16, k0 = 8 * g4;
            #pragma unroll
            for (int j = 0; j < 8; ++j) v[j] = bf16_rn(w0[(k0 + j) * 64 + n]);
        } else if (f < 12) {
            const int q = f - 4;
            const int n = (q >> 1) * 16 + r16, k0 = (q & 1) * 32 + 8 * g4;
            #pragma unroll
            for (int j = 0; j < 8; ++j) v[j] = bf16_rn(w1[(k0 + j) * 64 + n]);
        } else {
            const int n = r16, k0 = (f - 12) * 32 + 8 * g4;
            #pragma unroll
            for (int j = 0; j < 8; ++j)
                v[j] = (n < 3) ? bf16_rn(w2[(k0 + j) * 3 + n]) : (ushort)0;
        }
        #pragma unroll
        for (int j = 0; j < 8; ++j) wpf[e * 8 + j] = v[j];
    }
}

// ======================= K1: level-partitioned encode, pair loads ==========
// grid = 7 passes * chunks2 (2 pts/thread). pass 0 -> levels 0..9 (tables sum
// ~1.5 MB, L2-resident together); pass p>=1 -> level 9+p alone (owns L2).
// Dense levels: x-adjacent corners fetched with ONE 16B load (halves TCP
// line-requests, the measured bottleneck: ~1 line/cy/CU).
__global__ __launch_bounds__(256) void ngp_encode2_kernel(
    const float2* __restrict__ uv,
    const float2* __restrict__ table,
    uint32_t* __restrict__ xt,          // [16][n] packed (bf16 f0 | bf16 f1<<16)
    NGPParams p, int n, int chunks2)
{
    const int bid = blockIdx.x;
    const int pass = bid / chunks2;
    const int chunk = bid - pass * chunks2;
    const int base = chunk * 512 + threadIdx.x;

    float2 xy[2];
    #pragma unroll
    for (int q = 0; q < 2; ++q) {
        int idx = base + q * 256;
        xy[q] = uv[idx < n ? idx : (n - 1)];
    }

    const int l0 = (pass == 0) ? 0 : 9 + pass;
    const int l1 = (pass == 0) ? 9 : 9 + pass;

    for (int l = l0; l <= l1; ++l) {
        const float s = p.scale[l];
        const unsigned res = p.res[l];
        const bool hashed = (p.hashed_mask >> l) & 1u;
        const float2* tl = table + ((size_t)l << LOG2T);

        #pragma unroll
        for (int q = 0; q < 2; ++q) {
            const float px = xy[q].x * s + 0.5f;
            const float py = xy[q].y * s + 0.5f;
            const float fpx = floorf(px), fpy = floorf(py);
            const float fx = px - fpx, fy = py - fpy;
            const unsigned x0 = (unsigned)fpx, y0 = (unsigned)fpy;

            float2 c00, c10, c01, c11;
            if (!hashed) {
                // dense: indices never wrap (res^2 < T); corners x-adjacent.
                const unsigned b0 = x0 + y0 * res;
                const pairld q0 = *(const pairld*)(tl + b0);
                const pairld q1 = *(const pairld*)(tl + b0 + res);
                c00 = make_float2(q0.x, q0.y); c10 = make_float2(q0.z, q0.w);
                c01 = make_float2(q1.x, q1.y); c11 = make_float2(q1.z, q1.w);
            } else {
                const unsigned hy0 = y0 * PRIME_Y;
                const unsigned hy1 = (y0 + 1u) * PRIME_Y;
                if (!(x0 & 1u)) {
                    // x0 even: (x0^h) and ((x0+1)^h) differ only in bit 0.
                    const unsigned i0 = (x0 ^ hy0) & TMASK;
                    const unsigned i2 = (x0 ^ hy1) & TMASK;
                    const pairld q0 = *(const pairld*)(tl + (i0 & ~1u));
                    const pairld q2 = *(const pairld*)(tl + (i2 & ~1u));
                    if (i0 & 1u) { c00 = make_float2(q0.z, q0.w); c10 = make_float2(q0.x, q0.y); }
                    else         { c00 = make_float2(q0.x, q0.y); c10 = make_float2(q0.z, q0.w); }
                    if (i2 & 1u) { c01 = make_float2(q2.z, q2.w); c11 = make_float2(q2.x, q2.y); }
                    else         { c01 = make_float2(q2.x, q2.y); c11 = make_float2(q2.z, q2.w); }
                } else {
                    c00 = tl[(x0 ^ hy0) & TMASK];
                    c10 = tl[((x0 + 1u) ^ hy0) & TMASK];
                    c01 = tl[(x0 ^ hy1) & TMASK];
                    c11 = tl[((x0 + 1u) ^ hy1) & TMASK];
                }
            }

            const float w00 = (1.f - fx) * (1.f - fy);
            const float w10 = fx * (1.f - fy);
            const float w01 = (1.f - fx) * fy;
            const float w11 = fx * fy;
            const float f0 = w00 * c00.x + w10 * c10.x + w01 * c01.x + w11 * c11.x;
            const float f1 = w00 * c00.y + w10 * c10.y + w01 * c01.y + w11 * c11.y;
            const int idx = base + q * 256;
            if (idx < n) xt[(size_t)l * n + idx] = pack_bf16(f0, f1);
        }
    }
}

// ======================= K2: persistent MFMA MLP ===========================
// Weights live in VGPRs (14 A-frags/lane). Swapped-operand MFMA: D = W * X^T,
// so D col = point (lane&15), row = neuron (4*g4+reg): C-regs are 4
// consecutive neurons at one point -> H stores are packed ds_write_b64 and
// next layer's B-frag (H^T) is an aligned ds_read_b128 from H[pt][k].
// mfma_f32_16x16x32_bf16: A row=l&15, k=8*(l>>4)+j; B col=l&15, k=8*(l>>4)+j;
// C/D col=l&15, row=(l>>4)*4+reg  [measured m89].
__global__ __launch_bounds__(256, 2) void ngp_mlp_persist(
    const uint32_t* __restrict__ xt,
    const ushort* __restrict__ wpf,
    float* __restrict__ out, int n, int nchunks)
{
    __shared__ __align__(16) uint32_t Xl[2][16 * 256];  // double-buffered X: 32 KB
    __shared__ __align__(16) ushort  H[256 * 72];       // [pt][k] stride 72: 36 KB

    const int t = threadIdx.x;
    const int lane = t & 63;
    const int w = t >> 6;
    const int g4 = lane >> 4;
    const int r16 = lane & 15;

    // ---- weights -> registers (frag-major, coalesced 16B/lane) ----
    bf16x8 wf[NFRAG];
    #pragma unroll
    for (int f = 0; f < NFRAG; ++f)
        wf[f] = *(const bf16x8*)(wpf + (size_t)(f * 64 + lane) * 8);

    auto stage = [&](int cc, int bb) {
        if (((cc + 1) << 8) <= n) {
            #pragma unroll
            for (int i = 0; i < 4; ++i) {
                const int seg = i * 4 + w;
                const uint32_t* g = xt + (size_t)seg * n + (cc << 8) + (lane << 2);
                __builtin_amdgcn_global_load_lds(
                    (const __attribute__((address_space(1))) uint32_t*)g,
                    (__attribute__((address_space(3))) uint32_t*)&Xl[bb][seg << 8],
                    16, 0, 0);
            }
        } else {                       // tail chunk: guarded VGPR staging
            for (int seg = 0; seg < 16; ++seg) {
                const int pt = (cc << 8) + t;
                Xl[bb][(seg << 8) + t] = (pt < n) ? xt[(size_t)seg * n + pt] : 0u;
            }
        }
    };

    auto compute = [&](int cc, int bb) {
        // ---------------- layer 0: D0 = W0 (64x32) * X^T (32 x 256) -------
        #pragma unroll
        for (int mi = 0; mi < 4; ++mi) {
            const int plocal = (w * 4 + mi) * 16 + r16;   // this lane's point
            union { uint32_t u[4]; bf16x8 v; } cv;
            #pragma unroll
            for (int c = 0; c < 4; ++c)
                cv.u[c] = Xl[bb][((4 * g4 + c) << 8) + plocal];  // k = 8g4+2c,+1
            f32x4 a[4];
            #pragma unroll
            for (int nt = 0; nt < 4; ++nt)
                a[nt] = __builtin_amdgcn_mfma_f32_16x16x32_bf16(
                    wf[nt], cv.v, (f32x4){0.f, 0.f, 0.f, 0.f}, 0, 0, 0);
            const int pl = plocal * 72;
            #pragma unroll
            for (int nt = 0; nt < 4; ++nt) {
                const uint32_t d0 = pack_trunc(fmaxf(a[nt][1], 0.f), fmaxf(a[nt][0], 0.f));
                const uint32_t d1 = pack_trunc(fmaxf(a[nt][3], 0.f), fmaxf(a[nt][2], 0.f));
                *(uint2*)&H[pl + nt * 16 + 4 * g4] = make_uint2(d0, d1);
            }
        }
        // H rows are wave-private: no barrier.
        // ---------------- layers 1+2 per point-tile -----------------------
        #pragma unroll
        for (int mi = 0; mi < 4; ++mi) {
            const int plocal = (w * 4 + mi) * 16 + r16;
            const int pl = plocal * 72;
            const bf16x8 bh0 = *(const bf16x8*)&H[pl + 8 * g4];        // k 0..31
            const bf16x8 bh1 = *(const bf16x8*)&H[pl + 32 + 8 * g4];   // k 32..63
            #pragma unroll
            for (int nt = 0; nt < 4; ++nt) {
                f32x4 acc = __builtin_amdgcn_mfma_f32_16x16x32_bf16(
                    wf[4 + nt * 2], bh0, (f32x4){0.f, 0.f, 0.f, 0.f}, 0, 0, 0);
                acc = __builtin_amdgcn_mfma_f32_16x16x32_bf16(
                    wf[4 + nt * 2 + 1], bh1, acc, 0, 0, 0);
                const uint32_t d0 = pack_trunc(fmaxf(acc[1], 0.f), fmaxf(acc[0], 0.f));
                const uint32_t d1 = pack_trunc(fmaxf(acc[3], 0.f), fmaxf(acc[2], 0.f));
                *(uint2*)&H[pl + nt * 16 + 4 * g4] = make_uint2(d0, d1);  // H1 overwrites H0
            }
            const bf16x8 ch0 = *(const bf16x8*)&H[pl + 8 * g4];
            const bf16x8 ch1 = *(const bf16x8*)&H[pl + 32 + 8 * g4];
            f32x4 z = __builtin_amdgcn_mfma_f32_16x16x32_bf16(
                wf[12], ch0, (f32x4){0.f, 0.f, 0.f, 0.f}, 0, 0, 0);
            z = __builtin_amdgcn_mfma_f32_16x16x32_bf16(wf[13], ch1, z, 0, 0, 0);
            if (g4 == 0) {                       // rows n=0..2 live in g4==0
                const int pg = (cc << 8) + plocal;
                if (pg < n) {
                    #pragma unroll
                    for (int r = 0; r < 3; ++r)
                        out[(size_t)pg * 3 + r] = 1.f / (1.f + __expf(-z[r]));
                }
            }
        }
    };

    const int c0 = blockIdx.x;
    if (c0 < nchunks) stage(c0, 0);
    __syncthreads();
    int buf = 0;
    for (int c = c0; c < nchunks; c += gridDim.x) {
        const int cn = c + gridDim.x;
        if (cn < nchunks) stage(cn, buf ^ 1);   // prefetch flies under compute
        compute(c, buf);
        __syncthreads();                        // drains vmcnt + lgkm
        buf ^= 1;
    }
}

// ======================= fallback: round-1 fused kernel ====================
__global__ __launch_bounds__(256) void ngp_fused_kernel(
    const float2* __restrict__ uv,
    const float2* __restrict__ table,
    const float4* __restrict__ w0,
    const float4* __restrict__ w1,
    const float*  __restrict__ w2,
    float* __restrict__ out,
    NGPParams p, int n)
{
    __shared__ float4 sw0[512];
    __shared__ float4 sw1[1024];
    __shared__ float  sw2[192];
    const int t = threadIdx.x;
    #pragma unroll
    for (int i = 0; i < 2; i++) sw0[t + 256 * i] = w0[t + 256 * i];
    #pragma unroll
    for (int i = 0; i < 4; i++) sw1[t + 256 * i] = w1[t + 256 * i];
    if (t < 192) sw2[t] = w2[t];
    __syncthreads();
    const int gi = blockIdx.x * 256 + t;
    if (gi >= n) return;
    const float2 xy = uv[gi];
    float feat[32];
    #pragma unroll
    for (int l = 0; l < NLV; l++) {
        const float s = p.scale[l];
        const unsigned res = p.res[l];
        const float px = xy.x * s + 0.5f;
        const float py = xy.y * s + 0.5f;
        const float fpx = floorf(px), fpy = floorf(py);
        const float fx = px - fpx, fy = py - fpy;
        const unsigned x0 = (unsigned)fpx, y0 = (unsigned)fpy;
        unsigned i00, i10, i01, i11;
        if (!((p.hashed_mask >> l) & 1u)) {
            const unsigned b = x0 + y0 * res;
            i00 = b & TMASK; i10 = (b + 1u) & TMASK;
            i01 = (b + res) & TMASK; i11 = (b + res + 1u) & TMASK;
        } else {
            const unsigned hy0 = y0 * PRIME_Y;
            const unsigned hy1 = (y0 + 1u) * PRIME_Y;
            i00 = (x0 ^ hy0) & TMASK; i10 = ((x0 + 1u) ^ hy0) & TMASK;
            i01 = (x0 ^ hy1) & TMASK; i11 = ((x0 + 1u) ^ hy1) & TMASK;
        }
        const float2* tl = table + ((size_t)l << LOG2T);
        const float2 c00 = tl[i00], c10 = tl[i10], c01 = tl[i01], c11 = tl[i11];
        const float w00 = (1.f - fx) * (1.f - fy);
        const float w10 = fx * (1.f - fy);
        const float w01 = (1.f - fx) * fy;
        const float w11 = fx * fy;
        feat[2 * l]     = w00 * c00.x + w10 * c10.x + w01 * c01.x + w11 * c11.x;
        feat[2 * l + 1] = w00 * c00.y + w10 * c10.y + w01 * c01.y + w11 * c11.y;
    }
    float2 h0[32];
    #pragma unroll
    for (int j = 0; j < 32; j++) h0[j] = make_float2(0.f, 0.f);
    #pragma unroll
    for (int k = 0; k < 32; k++) {
        const float f = feat[k];
        #pragma unroll
        for (int j = 0; j < 16; j++) {
            const float4 ww = sw0[k * 16 + j];
            h0[2 * j].x = fmaf(f, ww.x, h0[2 * j].x);
            h0[2 * j].y = fmaf(f, ww.y, h0[2 * j].y);
            h0[2 * j + 1].x = fmaf(f, ww.z, h0[2 * j + 1].x);
            h0[2 * j + 1].y = fmaf(f, ww.w, h0[2 * j + 1].y);
        }
    }
    #pragma unroll
    for (int j = 0; j < 32; j++) {
        h0[j].x = fmaxf(h0[j].x, 0.f);
        h0[j].y = fmaxf(h0[j].y, 0.f);
    }
    float2 h1[32];
    #pragma unroll
    for (int j = 0; j < 32; j++) h1[j] = make_float2(0.f, 0.f);
    #pragma unroll
    for (int k = 0; k < 64; k++) {
        const float f = (k & 1) ? h0[k >> 1].y : h0[k >> 1].x;
        #pragma unroll
        for (int j = 0; j < 16; j++) {
            const float4 ww = sw1[k * 16 + j];
            h1[2 * j].x = fmaf(f, ww.x, h1[2 * j].x);
            h1[2 * j].y = fmaf(f, ww.y, h1[2 * j].y);
            h1[2 * j + 1].x = fmaf(f, ww.z, h1[2 * j + 1].x);
            h1[2 * j + 1].y = fmaf(f, ww.w, h1[2 * j + 1].y);
        }
    }
    #pragma unroll
    for (int j = 0; j < 32; j++) {
        h1[j].x = fmaxf(h1[j].x, 0.f);
        h1[j].y = fmaxf(h1[j].y, 0.f);
    }
    float z0 = 0.f, z1 = 0.f, z2 = 0.f;
    #pragma unroll
    for (int k = 0; k < 64; k++) {
        const float f = (k & 1) ? h1[k >> 1].y : h1[k >> 1].x;
        z0 = fmaf(f, sw2[3 * k + 0], z0);
        z1 = fmaf(f, sw2[3 * k + 1], z1);
        z2 = fmaf(f, sw2[3 * k + 2], z2);
    }
    out[3 * gi + 0] = 1.f / (1.f + __expf(-z0));
    out[3 * gi + 1] = 1.f / (1.f + __expf(-z1));
    out[3 * gi + 2] = 1.f / (1.f + __expf(-z2));
}

extern "C" void kernel_launch(void* const* d_in, const int* in_sizes, int n_in,
                              void* d_out, int out_size, void* d_ws, size_t ws_size,
                              hipStream_t stream) {
    const float2* uv    = (const float2*)d_in[0];
    const float2* table = (const float2*)d_in[1];
    const float*  w0f   = (const float*)d_in[2];
    const float*  w1f   = (const float*)d_in[3];
    const float*  w2f   = (const float*)d_in[4];
    float* out = (float*)d_out;

    const int n = in_sizes[0] / 2;

    NGPParams p;
    p.hashed_mask = 0;
    const double B = exp((log(2048.0) - log(16.0)) / 15.0);
    for (int l = 0; l < NLV; l++) {
        const double scale = 16.0 * pow(B, (double)l) - 1.0;
        const long long res = (long long)ceil(scale) + 1;
        p.scale[l] = (float)scale;
        p.res[l] = (unsigned)res;
        if (res * res > (long long)TSZ) p.hashed_mask |= (1u << l);
    }

    const size_t xt_bytes = (size_t)NLV * (size_t)n * 4u;
    const size_t need = xt_bytes + WPF_USHORTS * 2u;
    const int chunks = (n + 255) / 256;

    if (ws_size < need) {   // fallback: verified round-1 fused kernel
        ngp_fused_kernel<<<chunks, 256, 0, stream>>>(
            uv, table, (const float4*)w0f, (const float4*)w1f, w2f, out, p, n);
        return;
    }

    uint32_t* xt = (uint32_t*)d_ws;
    ushort* wpf = (ushort*)((char*)d_ws + xt_bytes);

    ngp_prep_wfrag<<<1, 256, 0, stream>>>(w0f, w1f, w2f, wpf);

    const int chunks2 = (n + 511) / 512;
    ngp_encode2_kernel<<<7 * chunks2, 256, 0, stream>>>(uv, table, xt, p, n, chunks2);

    const int nchunks = chunks;
    const int mlp_blocks = nchunks < 512 ? nchunks : 512;
    ngp_mlp_persist<<<mlp_blocks, 256, 0, stream>>>(xt, wpf, out, n, nchunks);
}